// Round 9
// baseline (58.048 us; speedup 1.0000x reference)
//
#include <hip/hip_runtime.h>

#define NSEG 4096

__device__ __forceinline__ void acc4(float4& a, const float4 v) {
    a.x += v.x; a.y += v.y; a.z += v.z; a.w += v.w;
}

// ---------- K0: scatter bounds table (R4-proven) ----------
__global__ __launch_bounds__(256) void setup_kernel(
    const int* __restrict__ seg,     // [nrows] sorted
    int*       __restrict__ bounds,  // [NSEG+1]
    int nrows)
{
    const int i = blockIdx.x * 256 + threadIdx.x;
    if (i >= nrows) return;
    const int cur  = seg[i];
    const int prev = (i == 0) ? -1 : seg[i - 1];
    for (int s = prev + 1; s <= cur; ++s) bounds[s] = i;
    if (i == nrows - 1) {
        for (int s = cur + 1; s <= NSEG; ++s) bounds[s] = nrows;
    }
}

// ---------- K1: R8 body + 62KB LDS residency cap (2 blocks/CU) ----------
// EXPERIMENT: same work, same per-block structure as round 8, but only
// 8 wave-streams/CU instead of 32 (4x fewer concurrent DRAM streams).
// Dynamic backfill over 4096 blocks keeps CUs fed and balanced.
__global__ __launch_bounds__(256) void fused_v2_kernel(
    const float* __restrict__ emb_a,
    const float* __restrict__ emb_b,
    const int*   __restrict__ bounds,  // [NSEG+1]
    const float* __restrict__ W,       // [32][512]
    const float* __restrict__ bias,    // [32]
    float*       __restrict__ out)     // [NSEG][32]
{
    const int s    = blockIdx.x;
    const int t    = threadIdx.x;
    const int wave = t >> 6;
    const int lane = t & 63;

    // 15872 floats = 62 KB: floor(160/62.1) = 2 blocks/CU residency cap.
    // Only [0..1023] are used as data.
    __shared__ float pooled[15872];
    __shared__ float sh_out[32];

    const int start = bounds[s];
    const int end   = bounds[s + 1];
    const int cnt   = end - start;
    const int mid   = start + (cnt >> 1);
    const int r0    = (wave >> 1) ? mid : start;
    const int r1    = (wave >> 1) ? end : mid;

    // ---- Phase 1: raw-sum pooling of this wave's quarter ----
    const float*  base = (wave & 1) ? emb_b : emb_a;
    const float4* src  = reinterpret_cast<const float4*>(base) + lane; // row stride 64 float4

    float4 a0{0,0,0,0}, a1{0,0,0,0}, a2{0,0,0,0}, a3{0,0,0,0};
    int r = r0;
    for (; r + 8 <= r1; r += 8) {
        float4 v0 = src[(size_t)(r+0)*64];
        float4 v1 = src[(size_t)(r+1)*64];
        float4 v2 = src[(size_t)(r+2)*64];
        float4 v3 = src[(size_t)(r+3)*64];
        float4 v4 = src[(size_t)(r+4)*64];
        float4 v5 = src[(size_t)(r+5)*64];
        float4 v6 = src[(size_t)(r+6)*64];
        float4 v7 = src[(size_t)(r+7)*64];
        acc4(a0, v0); acc4(a1, v1); acc4(a2, v2); acc4(a3, v3);
        acc4(a0, v4); acc4(a1, v5); acc4(a2, v6); acc4(a3, v7);
    }
    for (; r + 4 <= r1; r += 4) {
        float4 v0 = src[(size_t)(r+0)*64];
        float4 v1 = src[(size_t)(r+1)*64];
        float4 v2 = src[(size_t)(r+2)*64];
        float4 v3 = src[(size_t)(r+3)*64];
        acc4(a0, v0); acc4(a1, v1); acc4(a2, v2); acc4(a3, v3);
    }
    for (; r < r1; ++r) acc4(a0, src[(size_t)r * 64]);

    float4 acc;
    acc.x = a0.x + a1.x + a2.x + a3.x;
    acc.y = a0.y + a1.y + a2.y + a3.y;
    acc.z = a0.z + a1.z + a2.z + a3.z;
    acc.w = a0.w + a1.w + a2.w + a3.w;
    *reinterpret_cast<float4*>(pooled + (wave << 8) + (lane << 2)) = acc;
    __syncthreads();

    // ---- Combine halves + scale ----
    const float inv = 1.0f / (float)max(cnt, 1);
    const float4* pool4 = reinterpret_cast<const float4*>(pooled);
    const float4 qa0 = pool4[lane];         // emb_a, first half  (wave 0)
    const float4 qb0 = pool4[64 + lane];    // emb_b, first half  (wave 1)
    const float4 qa1 = pool4[128 + lane];   // emb_a, second half (wave 2)
    const float4 qb1 = pool4[192 + lane];   // emb_b, second half (wave 3)
    float4 p0, p1;
    p0.x = (qa0.x + qa1.x) * inv;  p0.y = (qa0.y + qa1.y) * inv;
    p0.z = (qa0.z + qa1.z) * inv;  p0.w = (qa0.w + qa1.w) * inv;
    p1.x = (qb0.x + qb1.x) * inv;  p1.y = (qb0.y + qb1.y) * inv;
    p1.z = (qb0.z + qb1.z) * inv;  p1.w = (qb0.w + qb1.w) * inv;

    // ---- Phase 2: projection, wave w owns j in [8w, 8w+8) ----
    #pragma unroll 4
    for (int jj = 0; jj < 8; ++jj) {
        const int j = (wave << 3) + jj;
        const float4* wrow = reinterpret_cast<const float4*>(W + j * 512);
        const float4  w0 = wrow[lane];        // d 0..255, 1KB wave-load (L1-hot)
        const float4  w1 = wrow[64 + lane];   // d 256..511
        float v = p0.x*w0.x + p0.y*w0.y + p0.z*w0.z + p0.w*w0.w
                + p1.x*w1.x + p1.y*w1.y + p1.z*w1.z + p1.w*w1.w;
        v += __shfl_xor(v, 1);
        v += __shfl_xor(v, 2);
        v += __shfl_xor(v, 4);
        v += __shfl_xor(v, 8);
        v += __shfl_xor(v, 16);
        v += __shfl_xor(v, 32);
        if (lane == 0) sh_out[j] = v + bias[j];
    }
    __syncthreads();

    if (t < 32) out[s * 32 + t] = sh_out[t];
}

// ---------- Fallback (ws too small): round-8 kernel verbatim (39.6 us) ----------
__global__ __launch_bounds__(256, 8) void fused_fallback_kernel(
    const float* __restrict__ emb_a,
    const float* __restrict__ emb_b,
    const int*   __restrict__ seg,
    const float* __restrict__ W,
    const float* __restrict__ bias,
    float*       __restrict__ out,
    int nrows)
{
    const int s    = blockIdx.x;
    const int t    = threadIdx.x;
    const int wave = t >> 6;
    const int lane = t & 63;

    __shared__ int   bnd[2];
    __shared__ float pooled[1024];
    __shared__ float sh_out[32];

    if (t < 2) {
        int target = s + t;
        int lo = 0, hi = nrows;
        while (lo < hi) {
            int mid = (lo + hi) >> 1;
            if (seg[mid] < target) lo = mid + 1; else hi = mid;
        }
        bnd[t] = lo;
    }
    __syncthreads();
    const int start = bnd[0];
    const int end   = bnd[1];
    const int cnt   = end - start;
    const int mid   = start + (cnt >> 1);
    const int r0    = (wave >> 1) ? mid : start;
    const int r1    = (wave >> 1) ? end : mid;

    const float*  base = (wave & 1) ? emb_b : emb_a;
    const float4* src  = reinterpret_cast<const float4*>(base) + lane;

    float4 a0{0,0,0,0}, a1{0,0,0,0}, a2{0,0,0,0}, a3{0,0,0,0};
    int r = r0;
    for (; r + 8 <= r1; r += 8) {
        float4 v0 = src[(size_t)(r+0)*64];
        float4 v1 = src[(size_t)(r+1)*64];
        float4 v2 = src[(size_t)(r+2)*64];
        float4 v3 = src[(size_t)(r+3)*64];
        float4 v4 = src[(size_t)(r+4)*64];
        float4 v5 = src[(size_t)(r+5)*64];
        float4 v6 = src[(size_t)(r+6)*64];
        float4 v7 = src[(size_t)(r+7)*64];
        acc4(a0, v0); acc4(a1, v1); acc4(a2, v2); acc4(a3, v3);
        acc4(a0, v4); acc4(a1, v5); acc4(a2, v6); acc4(a3, v7);
    }
    for (; r + 4 <= r1; r += 4) {
        float4 v0 = src[(size_t)(r+0)*64];
        float4 v1 = src[(size_t)(r+1)*64];
        float4 v2 = src[(size_t)(r+2)*64];
        float4 v3 = src[(size_t)(r+3)*64];
        acc4(a0, v0); acc4(a1, v1); acc4(a2, v2); acc4(a3, v3);
    }
    for (; r < r1; ++r) acc4(a0, src[(size_t)r * 64]);

    float4 acc;
    acc.x = a0.x + a1.x + a2.x + a3.x;
    acc.y = a0.y + a1.y + a2.y + a3.y;
    acc.z = a0.z + a1.z + a2.z + a3.z;
    acc.w = a0.w + a1.w + a2.w + a3.w;
    *reinterpret_cast<float4*>(pooled + (wave << 8) + (lane << 2)) = acc;
    __syncthreads();

    const float inv = 1.0f / (float)max(cnt, 1);
    const float4* pool4 = reinterpret_cast<const float4*>(pooled);
    const float4 qa0 = pool4[lane];
    const float4 qb0 = pool4[64 + lane];
    const float4 qa1 = pool4[128 + lane];
    const float4 qb1 = pool4[192 + lane];
    float4 p0, p1;
    p0.x = (qa0.x + qa1.x) * inv;  p0.y = (qa0.y + qa1.y) * inv;
    p0.z = (qa0.z + qa1.z) * inv;  p0.w = (qa0.w + qa1.w) * inv;
    p1.x = (qb0.x + qb1.x) * inv;  p1.y = (qb0.y + qb1.y) * inv;
    p1.z = (qb0.z + qb1.z) * inv;  p1.w = (qb0.w + qb1.w) * inv;

    #pragma unroll 4
    for (int jj = 0; jj < 8; ++jj) {
        const int j = (wave << 3) + jj;
        const float4* wrow = reinterpret_cast<const float4*>(W + j * 512);
        const float4  w0 = wrow[lane];
        const float4  w1 = wrow[64 + lane];
        float v = p0.x*w0.x + p0.y*w0.y + p0.z*w0.z + p0.w*w0.w
                + p1.x*w1.x + p1.y*w1.y + p1.z*w1.z + p1.w*w1.w;
        v += __shfl_xor(v, 1);
        v += __shfl_xor(v, 2);
        v += __shfl_xor(v, 4);
        v += __shfl_xor(v, 8);
        v += __shfl_xor(v, 16);
        v += __shfl_xor(v, 32);
        if (lane == 0) sh_out[j] = v + bias[j];
    }
    __syncthreads();

    if (t < 32) out[s * 32 + t] = sh_out[t];
}

extern "C" void kernel_launch(void* const* d_in, const int* in_sizes, int n_in,
                              void* d_out, int out_size, void* d_ws, size_t ws_size,
                              hipStream_t stream) {
    const float* emb_a = (const float*)d_in[0];
    const float* emb_b = (const float*)d_in[1];
    const int*   seg   = (const int*)d_in[2];
    const float* W     = (const float*)d_in[3];
    const float* bias  = (const float*)d_in[4];
    float*       out   = (float*)d_out;
    const int nrows = in_sizes[2];

    const size_t need = (size_t)(NSEG + 1) * sizeof(int);
    if (ws_size >= need) {
        int* bounds = (int*)d_ws;
        setup_kernel<<<(nrows + 255) / 256, 256, 0, stream>>>(seg, bounds, nrows);
        fused_v2_kernel<<<NSEG, 256, 0, stream>>>(emb_a, emb_b, bounds, W, bias, out);
    } else {
        fused_fallback_kernel<<<NSEG, 256, 0, stream>>>(emb_a, emb_b, seg, W, bias, out, nrows);
    }
}

// Round 10
// 39.842 us; speedup vs baseline: 1.4570x; 1.4570x over previous
//
#include <hip/hip_runtime.h>

#define NSEG 4096

__device__ __forceinline__ void acc4(float4& a, const float4 v) {
    a.x += v.x; a.y += v.y; a.z += v.z; a.w += v.w;
}

// Round-8 kernel + XCD-aware blockIdx swizzle (the ONLY change).
// 4096 blocks x 256 thr (4 waves), 8 blocks/CU residency.
// Swizzle: XCD x (bid%8) owns contiguous segment range [512x, 512x+512),
// so each XCD's L2 streams one contiguous 16MB window instead of 8
// interleaved scatter-streams. nwg=4096 % 8 == 0 -> bijective.
__global__ __launch_bounds__(256, 8) void fused_swz_kernel(
    const float* __restrict__ emb_a,
    const float* __restrict__ emb_b,
    const int*   __restrict__ seg,     // [nrows] sorted ascending
    const float* __restrict__ W,       // [32][512]
    const float* __restrict__ bias,    // [32]
    float*       __restrict__ out,     // [NSEG][32]
    int nrows)
{
    // XCD-aware swizzle: consecutive s -> same XCD chunk.
    const int bid = blockIdx.x;
    const int s   = (bid & 7) * (NSEG / 8) + (bid >> 3);

    const int t    = threadIdx.x;
    const int wave = t >> 6;
    const int lane = t & 63;

    __shared__ int   bnd[2];
    __shared__ float pooled[1024];   // [4 waves][256 cols] raw sums
    __shared__ float sh_out[32];

    // ---- segment bounds via lower_bound (16 iters, L1/L2-cached) ----
    if (t < 2) {
        int target = s + t;
        int lo = 0, hi = nrows;
        while (lo < hi) {
            int mid = (lo + hi) >> 1;
            if (seg[mid] < target) lo = mid + 1; else hi = mid;
        }
        bnd[t] = lo;
    }
    __syncthreads();
    const int start = bnd[0];
    const int end   = bnd[1];
    const int cnt   = end - start;
    const int mid   = start + (cnt >> 1);
    const int r0    = (wave >> 1) ? mid : start;
    const int r1    = (wave >> 1) ? end : mid;

    // ---- Phase 1: raw-sum pooling of this wave's quarter ----
    const float*  base = (wave & 1) ? emb_b : emb_a;
    const float4* src  = reinterpret_cast<const float4*>(base) + lane; // row stride 64 float4

    float4 a0{0,0,0,0}, a1{0,0,0,0}, a2{0,0,0,0}, a3{0,0,0,0};
    int r = r0;
    for (; r + 8 <= r1; r += 8) {
        float4 v0 = src[(size_t)(r+0)*64];
        float4 v1 = src[(size_t)(r+1)*64];
        float4 v2 = src[(size_t)(r+2)*64];
        float4 v3 = src[(size_t)(r+3)*64];
        float4 v4 = src[(size_t)(r+4)*64];
        float4 v5 = src[(size_t)(r+5)*64];
        float4 v6 = src[(size_t)(r+6)*64];
        float4 v7 = src[(size_t)(r+7)*64];
        acc4(a0, v0); acc4(a1, v1); acc4(a2, v2); acc4(a3, v3);
        acc4(a0, v4); acc4(a1, v5); acc4(a2, v6); acc4(a3, v7);
    }
    for (; r + 4 <= r1; r += 4) {
        float4 v0 = src[(size_t)(r+0)*64];
        float4 v1 = src[(size_t)(r+1)*64];
        float4 v2 = src[(size_t)(r+2)*64];
        float4 v3 = src[(size_t)(r+3)*64];
        acc4(a0, v0); acc4(a1, v1); acc4(a2, v2); acc4(a3, v3);
    }
    for (; r < r1; ++r) acc4(a0, src[(size_t)r * 64]);

    float4 acc;
    acc.x = a0.x + a1.x + a2.x + a3.x;
    acc.y = a0.y + a1.y + a2.y + a3.y;
    acc.z = a0.z + a1.z + a2.z + a3.z;
    acc.w = a0.w + a1.w + a2.w + a3.w;
    *reinterpret_cast<float4*>(pooled + (wave << 8) + (lane << 2)) = acc;
    __syncthreads();

    // ---- Combine halves + scale ----
    const float inv = 1.0f / (float)max(cnt, 1);
    const float4* pool4 = reinterpret_cast<const float4*>(pooled);
    const float4 qa0 = pool4[lane];         // emb_a, first half  (wave 0)
    const float4 qb0 = pool4[64 + lane];    // emb_b, first half  (wave 1)
    const float4 qa1 = pool4[128 + lane];   // emb_a, second half (wave 2)
    const float4 qb1 = pool4[192 + lane];   // emb_b, second half (wave 3)
    float4 p0, p1;
    p0.x = (qa0.x + qa1.x) * inv;  p0.y = (qa0.y + qa1.y) * inv;
    p0.z = (qa0.z + qa1.z) * inv;  p0.w = (qa0.w + qa1.w) * inv;
    p1.x = (qb0.x + qb1.x) * inv;  p1.y = (qb0.y + qb1.y) * inv;
    p1.z = (qb0.z + qb1.z) * inv;  p1.w = (qb0.w + qb1.w) * inv;

    // ---- Phase 2: projection, wave w owns j in [8w, 8w+8) ----
    #pragma unroll 4
    for (int jj = 0; jj < 8; ++jj) {
        const int j = (wave << 3) + jj;
        const float4* wrow = reinterpret_cast<const float4*>(W + j * 512);
        const float4  w0 = wrow[lane];        // d 0..255, 1KB wave-load (L1-hot)
        const float4  w1 = wrow[64 + lane];   // d 256..511
        float v = p0.x*w0.x + p0.y*w0.y + p0.z*w0.z + p0.w*w0.w
                + p1.x*w1.x + p1.y*w1.y + p1.z*w1.z + p1.w*w1.w;
        v += __shfl_xor(v, 1);
        v += __shfl_xor(v, 2);
        v += __shfl_xor(v, 4);
        v += __shfl_xor(v, 8);
        v += __shfl_xor(v, 16);
        v += __shfl_xor(v, 32);
        if (lane == 0) sh_out[j] = v + bias[j];
    }
    __syncthreads();

    // One coalesced 128B store per block.
    if (t < 32) out[s * 32 + t] = sh_out[t];
}

extern "C" void kernel_launch(void* const* d_in, const int* in_sizes, int n_in,
                              void* d_out, int out_size, void* d_ws, size_t ws_size,
                              hipStream_t stream) {
    const float* emb_a = (const float*)d_in[0];
    const float* emb_b = (const float*)d_in[1];
    const int*   seg   = (const int*)d_in[2];
    const float* W     = (const float*)d_in[3];
    const float* bias  = (const float*)d_in[4];
    float*       out   = (float*)d_out;
    const int nrows = in_sizes[2];

    fused_swz_kernel<<<NSEG, 256, 0, stream>>>(emb_a, emb_b, seg, W, bias, out, nrows);
}